// Round 21
// baseline (164.055 us; speedup 1.0000x reference)
//
#include <hip/hip_runtime.h>
#include <cstdint>
#include <math.h>

#define TT 2048
#define DD 2048
#define NH 16
#define NKV 4
#define HD 128
#define SCALE_F 0.08838834764831845f
#define LOG2E 1.4426950408889634f

#if __has_builtin(__builtin_amdgcn_exp2f)
#define EXP2(x) __builtin_amdgcn_exp2f(x)
#else
#define EXP2(x) exp2f(x)
#endif

typedef int   i32x4 __attribute__((ext_vector_type(4)));
typedef float f32x4 __attribute__((ext_vector_type(4)));
typedef short s16x8 __attribute__((ext_vector_type(8)));

__device__ __forceinline__ i32x4 mfma_i8(i32x4 a, i32x4 b, i32x4 c) {
  return __builtin_amdgcn_mfma_i32_16x16x64_i8(a, b, c, 0, 0, 0);
}
__device__ __forceinline__ f32x4 mfma_bf16(s16x8 a, s16x8 b, f32x4 c) {
  return __builtin_amdgcn_mfma_f32_16x16x32_bf16(a, b, c, 0, 0, 0);
}
__device__ __forceinline__ uint32_t fbits(float f) {
  union { float f; uint32_t u; } x; x.f = f; return x.u;
}
__device__ __forceinline__ float bf16_to_f(ushort h) {
  union { uint32_t u; float f; } x; x.u = ((uint32_t)h) << 16; return x.f;
}

// ---------------------------------------------------------------------------
// Kernel 1: rowwise int8 quantization for x/wq/wk/wv + fused RoPE table.
// (verified round 18)
// ---------------------------------------------------------------------------
__global__ __launch_bounds__(256)
void quant_rows_kernel(const float* __restrict__ x, const float* __restrict__ wq,
                       const float* __restrict__ wk, const float* __restrict__ wv,
                       int8_t* __restrict__ qx, float* __restrict__ xs,
                       int8_t* __restrict__ qwq, float* __restrict__ wqs,
                       int8_t* __restrict__ qwk, float* __restrict__ wks,
                       int8_t* __restrict__ qwv, float* __restrict__ wvs,
                       float2* __restrict__ ropet) {
  int r = blockIdx.x;
  int tid = threadIdx.x;
  if (r >= 5120) {                       // RoPE table branch (uniform per block)
    int idx = (r - 5120) * 256 + tid;    // 0..131071
    int t = idx >> 6, d = idx & 63;
    float inv = 1.0f / powf(1000000.0f, (float)d * (1.0f/64.0f));
    float sn, cs;
    sincosf((float)t * inv, &sn, &cs);
    ropet[idx] = make_float2(cs, sn);
    return;
  }
  const float* src; int8_t* dst; float* sc; int row;
  if (r < 2048)      { src = x;  dst = qx;  sc = xs;  row = r; }
  else if (r < 4096) { src = wq; dst = qwq; sc = wqs; row = r - 2048; }
  else if (r < 4608) { src = wk; dst = qwk; sc = wks; row = r - 4096; }
  else               { src = wv; dst = qwv; sc = wvs; row = r - 4608; }
  src += (size_t)row * DD; dst += (size_t)row * DD;
  float4 v0 = ((const float4*)src)[2*tid];
  float4 v1 = ((const float4*)src)[2*tid+1];
  float m = fmaxf(fmaxf(fmaxf(fabsf(v0.x), fabsf(v0.y)), fmaxf(fabsf(v0.z), fabsf(v0.w))),
                  fmaxf(fmaxf(fabsf(v1.x), fabsf(v1.y)), fmaxf(fabsf(v1.z), fabsf(v1.w))));
  #pragma unroll
  for (int off = 1; off < 64; off <<= 1) m = fmaxf(m, __shfl_xor(m, off));
  __shared__ float wmax[4];
  if ((tid & 63) == 0) wmax[tid >> 6] = m;
  __syncthreads();
  m = fmaxf(fmaxf(wmax[0], wmax[1]), fmaxf(wmax[2], wmax[3]));
  float s = fmaxf(m / 127.0f, 1e-8f);
  if (tid == 0) sc[row] = s;
  float vv[8] = {v0.x, v0.y, v0.z, v0.w, v1.x, v1.y, v1.z, v1.w};
  uint32_t p0 = 0, p1 = 0;
  #pragma unroll
  for (int i = 0; i < 4; ++i) {
    int q = (int)fminf(fmaxf(rintf(vv[i] / s), -127.0f), 127.0f);
    p0 |= ((uint32_t)q & 0xffu) << (8*i);
  }
  #pragma unroll
  for (int i = 0; i < 4; ++i) {
    int q = (int)fminf(fmaxf(rintf(vv[4+i] / s), -127.0f), 127.0f);
    p1 |= ((uint32_t)q & 0xffu) << (8*i);
  }
  ((uint2*)dst)[tid] = make_uint2(p0, p1);
}

// ---------------------------------------------------------------------------
// Kernel 2: i8-MFMA projection GEMM + dequant + RoPE(table) + requant.
// (verified round 18: 4 waves, wave owns 16 t-rows x 128 o-cols)
// ---------------------------------------------------------------------------
__global__ __launch_bounds__(256)
void proj_kernel(const int8_t* __restrict__ qx, const float* __restrict__ xs,
                 const int8_t* __restrict__ qwq, const float* __restrict__ wqs,
                 const int8_t* __restrict__ qwk, const float* __restrict__ wks,
                 const int8_t* __restrict__ qwv, const float* __restrict__ wvs,
                 const float2* __restrict__ ropet,
                 int8_t* __restrict__ qq, float* __restrict__ qsc_out,
                 int8_t* __restrict__ kq, float* __restrict__ ksc_out,
                 int8_t* __restrict__ vq, float* __restrict__ vsc_out) {
  int id  = blockIdx.x;          // 0..767
  int xcd = id & 7;
  int j   = id >> 3;             // 0..95
  int hg  = xcd >> 1;
  int th  = xcd & 1;
  int gh  = hg*6 + (j % 6);      // 0..23
  int tb  = th*16 + (j / 6);     // 0..31
  int t0  = tb * 64;

  const int8_t* wgt; const float* wsc; int8_t* outq; float* outs; bool doRope;
  if (gh < NH) {
    wgt = qwq + (size_t)gh*HD*DD; wsc = wqs + gh*HD;
    outq = qq + (size_t)gh*TT*HD; outs = qsc_out + (size_t)gh*TT; doRope = true;
  } else if (gh < NH + NKV) {
    int hh = gh - NH;
    wgt = qwk + (size_t)hh*HD*DD; wsc = wks + hh*HD;
    outq = kq + (size_t)hh*TT*HD; outs = ksc_out + (size_t)hh*TT; doRope = true;
  } else {
    int hh = gh - NH - NKV;
    wgt = qwv + (size_t)hh*HD*DD; wsc = wvs + hh*HD;
    outq = vq + (size_t)hh*TT*HD; outs = vsc_out + (size_t)hh*TT; doRope = false;
  }

  __shared__ int8_t As[64 * 144];
  __shared__ int8_t Bs[128 * 144];
  int tid = threadIdx.x;
  int w  = tid >> 6;    // wave 0..3: t rows w*16 .. +15
  int l  = tid & 63;
  int lg = l & 15;
  int lh = l >> 4;

  i32x4 acc[8];
  #pragma unroll
  for (int tj = 0; tj < 8; ++tj) acc[tj] = (i32x4){0,0,0,0};

  i32x4 prefA[2], prefB[4];

#define PROJ_ISSUE(KT)                                                          \
  {                                                                             \
    int kk0 = (KT) * 128;                                                       \
    _Pragma("unroll")                                                           \
    for (int i = 0; i < 2; ++i) {                                               \
      int idx = tid + i*256, r = idx >> 3, c = idx & 7;                         \
      prefA[i] = *(const i32x4*)&qx[(size_t)(t0 + r)*DD + kk0 + c*16];          \
    }                                                                           \
    _Pragma("unroll")                                                           \
    for (int i = 0; i < 4; ++i) {                                               \
      int idx = tid + i*256, r = idx >> 3, c = idx & 7;                         \
      prefB[i] = *(const i32x4*)&wgt[(size_t)r*DD + kk0 + c*16];                \
    }                                                                           \
  }

  PROJ_ISSUE(0);

  for (int kt = 0; kt < DD/128; ++kt) {
    __syncthreads();
    #pragma unroll
    for (int i = 0; i < 2; ++i) {
      int idx = tid + i*256, r = idx >> 3, c = idx & 7;
      *(i32x4*)&As[r*144 + c*16] = prefA[i];
    }
    #pragma unroll
    for (int i = 0; i < 4; ++i) {
      int idx = tid + i*256, r = idx >> 3, c = idx & 7;
      *(i32x4*)&Bs[r*144 + c*16] = prefB[i];
    }
    __syncthreads();
    if (kt + 1 < DD/128) PROJ_ISSUE(kt + 1);

    #pragma unroll
    for (int s = 0; s < 2; ++s) {
      i32x4 a0 = *(const i32x4*)&As[(w*16 + lg)*144 + s*64 + lh*16];
      #pragma unroll
      for (int tj = 0; tj < 8; ++tj) {
        i32x4 b = *(const i32x4*)&Bs[(tj*16 + lg)*144 + s*64 + lh*16];
        acc[tj] = mfma_i8(a0, b, acc[tj]);
      }
    }
  }
#undef PROJ_ISSUE

  float y[8][4];
  #pragma unroll
  for (int rr = 0; rr < 4; ++rr) {
    int tl = w*16 + lh*4 + rr;
    float xsi = xs[t0 + tl];
    #pragma unroll
    for (int tj = 0; tj < 8; ++tj)
      y[tj][rr] = (float)acc[tj][rr] * xsi * wsc[tj*16 + lg];
  }

  if (doRope) {
    #pragma unroll
    for (int rr = 0; rr < 4; ++rr) {
      int trow = t0 + w*16 + lh*4 + rr;
      const float2* tr = &ropet[trow * 64];
      #pragma unroll
      for (int tj = 0; tj < 4; ++tj) {
        float2 cssn = tr[tj*16 + lg];
        float lo = y[tj][rr], hi = y[tj+4][rr];
        y[tj][rr]   = lo*cssn.x - hi*cssn.y;
        y[tj+4][rr] = hi*cssn.x + lo*cssn.y;
      }
    }
  }

  __syncthreads();
  #pragma unroll
  for (int rr = 0; rr < 4; ++rr) {
    int tl = w*16 + lh*4 + rr;
    float mx = fabsf(y[0][rr]);
    #pragma unroll
    for (int tj = 1; tj < 8; ++tj) mx = fmaxf(mx, fabsf(y[tj][rr]));
    mx = fmaxf(mx, __shfl_xor(mx, 1));
    mx = fmaxf(mx, __shfl_xor(mx, 2));
    mx = fmaxf(mx, __shfl_xor(mx, 4));
    mx = fmaxf(mx, __shfl_xor(mx, 8));
    float s = fmaxf(mx / 127.0f, 1e-8f);
    if (lg == 0) outs[t0 + tl] = s;
    #pragma unroll
    for (int tj = 0; tj < 8; ++tj) {
      int qv = (int)fminf(fmaxf(rintf(y[tj][rr] / s), -127.0f), 127.0f);
      As[tl*144 + tj*16 + lg] = (int8_t)qv;
    }
  }
  __syncthreads();
  #pragma unroll
  for (int i = 0; i < 2; ++i) {
    int idx = tid + i*256, r = idx >> 3, c = idx & 7;
    *(i32x4*)&outq[(size_t)(t0 + r)*HD + c*16] = *(const i32x4*)&As[r*144 + c*16];
  }
}

// ---------------------------------------------------------------------------
// Kernel 3: MFMA flash attention. Round 21: KB=128 per iteration (halves
// barriers/softmax passes; max 6 iters/chunk), Pf eliminated via the
// r17-verified in-register P redistribution extended to kb=0..3.
// Chunk classes and partial-slot format unchanged. T13 defer-max kept.
// ---------------------------------------------------------------------------
__global__ __launch_bounds__(512)
void attn_mfma_kernel(const int8_t* __restrict__ qq, const float* __restrict__ qsc_in,
                      const int8_t* __restrict__ kq, const float* __restrict__ ksc_in,
                      const int8_t* __restrict__ vq, const float* __restrict__ vsc_in,
                      float* __restrict__ ao,
                      float* __restrict__ opA, float* __restrict__ opB,
                      float* __restrict__ ml) {
  int id = blockIdx.x;              // 0..479
  int h   = id / 30;
  int loc = id % 30;
  int qb2, c;
  if (loc < 12)      { qb2 = 15 - loc/3;        c = loc % 3; }
  else if (loc < 24) { qb2 = 11 - (loc - 12)/2; c = (loc - 12) % 2; }
  else               { qb2 = 5 - (loc - 24);    c = 0; }
  int nkt2 = qb2 + 1;               // 128-wide K tiles
  int nc  = (qb2 <= 5) ? 1 : ((qb2 <= 11) ? 2 : 3);
  int ktb = (c * nkt2) / nc;
  int kte = ((c + 1) * nkt2) / nc;
  int hk  = h >> 2;
  int qb0 = qb2 * 128;

  __shared__ int8_t Ks[128 * 144];   // [k][d], 144B stride
  __shared__ ushort Vt[128 * 136];   // [d][k] bf16, 136-elem stride

  int tid = threadIdx.x;
  int w  = tid >> 6;    // 0..7
  int l  = tid & 63;
  int lg = l & 15;
  int lh = l >> 4;

  const int8_t* qp = &qq[((size_t)h*TT + qb0 + 16*w + lg)*HD + lh*16];
  i32x4 qa0 = *(const i32x4*)qp;
  i32x4 qa1 = *(const i32x4*)(qp + 64);

  int myq = qb0 + 16*w + lg;
  float qsl = qsc_in[(size_t)h*TT + myq] * (SCALE_F * LOG2E);

  float mrun = -1e30f, lrun = 0.f;
  f32x4 acc_o[8];
  #pragma unroll
  for (int dt = 0; dt < 8; ++dt) acc_o[dt] = (f32x4){0.f, 0.f, 0.f, 0.f};

  // staging: K: 128 rows x 32B/thread; V: key-pair 2*m2, 16 d's per thread
  int srow = tid >> 2, scol = (tid & 3) * 32;
  int m2 = tid & 63, d0v = (tid >> 6) * 16;

  i32x4 kregA, kregB;
  int2  vr0a, vr0b, vr1a, vr1b;

#define ISSUE_LOADS(KT)                                                         \
  {                                                                             \
    int kk0 = (KT) * 128;                                                       \
    const int8_t* kp0 = &kq[((size_t)hk*TT + kk0 + srow)*HD + scol];            \
    kregA = *(const i32x4*)kp0;                                                 \
    kregB = *(const i32x4*)(kp0 + 16);                                          \
    const int8_t* vp = &vq[((size_t)hk*TT + kk0 + 2*m2)*HD + d0v];              \
    vr0a = *(const int2*)vp;        vr0b = *(const int2*)(vp + 8);              \
    vr1a = *(const int2*)(vp + HD); vr1b = *(const int2*)(vp + HD + 8);         \
  }

  ISSUE_LOADS(ktb);

  for (int kt = ktb; kt < kte; ++kt) {
    int k0 = kt * 128;
    __syncthreads();
    *(i32x4*)&Ks[srow*144 + scol]      = kregA;
    *(i32x4*)&Ks[srow*144 + scol + 16] = kregB;
    // V: int8 -> bf16, transposed store (keys 2*m2, 2*m2+1 packed per u32)
#define VPACK(W0, W1, BASE)                                                     \
    _Pragma("unroll")                                                           \
    for (int jj = 0; jj < 4; ++jj) {                                            \
      int a0 = ((W0) << (24 - 8*jj)) >> 24;                                     \
      int b0 = ((W1) << (24 - 8*jj)) >> 24;                                     \
      *(uint32_t*)&Vt[(d0v + (BASE) + jj)*136 + 2*m2] =                         \
          (fbits((float)a0) >> 16) | ((fbits((float)b0) >> 16) << 16);          \
    }
    VPACK(vr0a.x, vr1a.x, 0)
    VPACK(vr0a.y, vr1a.y, 4)
    VPACK(vr0b.x, vr1b.x, 8)
    VPACK(vr0b.y, vr1b.y, 12)
#undef VPACK
    __syncthreads();
    if (kt + 1 < kte) ISSUE_LOADS(kt + 1);

    // ---- swapped scores: 8 tiles of 16 keys ----
    i32x4 sacc[8];
    #pragma unroll
    for (int t = 0; t < 8; ++t) sacc[t] = (i32x4){0, 0, 0, 0};
    __builtin_amdgcn_s_setprio(1);
    #pragma unroll
    for (int t = 0; t < 8; ++t) {
      const int8_t* kp = &Ks[(16*t + lg)*144 + lh*16];
      i32x4 b0 = *(const i32x4*)kp;
      i32x4 b1 = *(const i32x4*)(kp + 64);
      sacc[t] = mfma_i8(b0, qa0, sacc[t]);
      sacc[t] = mfma_i8(b1, qa1, sacc[t]);
    }
    __builtin_amdgcn_s_setprio(0);

    f32x4 ksv4[8], vsv4[8];
    #pragma unroll
    for (int t = 0; t < 8; ++t) {
      ksv4[t] = *(const f32x4*)&ksc_in[(size_t)hk*TT + k0 + 16*t + 4*lh];
      vsv4[t] = *(const f32x4*)&vsc_in[(size_t)hk*TT + k0 + 16*t + 4*lh];
    }

    bool maskTile = (kt == nkt2 - 1);   // diagonal lives in the last 128-tile
    float sf[8][4];
    #pragma unroll
    for (int t = 0; t < 8; ++t)
      #pragma unroll
      for (int rr = 0; rr < 4; ++rr) {
        float v = (float)sacc[t][rr] * qsl * ksv4[t][rr];
        if (maskTile) {
          int kkg = k0 + 16*t + 4*lh + rr;
          v = (kkg <= myq) ? v : -1e30f;
        }
        sf[t][rr] = v;
      }

    float rm = sf[0][0];
    #pragma unroll
    for (int t = 0; t < 8; ++t)
      #pragma unroll
      for (int rr = 0; rr < 4; ++rr) rm = fmaxf(rm, sf[t][rr]);
    rm = fmaxf(rm, __shfl_xor(rm, 16));
    rm = fmaxf(rm, __shfl_xor(rm, 32));

    // T13 defer-max
    bool defer = __all(rm <= mrun + 8.0f && mrun > -1e29f);
    float mnew, corr;
    if (defer) { mnew = mrun; corr = 1.0f; }
    else       { mnew = fmaxf(mrun, rm); corr = EXP2(mrun - mnew); mrun = mnew; }

    float p[8][4];
    float ps = 0.f;
    #pragma unroll
    for (int t = 0; t < 8; ++t)
      #pragma unroll
      for (int rr = 0; rr < 4; ++rr) { p[t][rr] = EXP2(sf[t][rr] - mnew); ps += p[t][rr]; }
    ps += __shfl_xor(ps, 16);
    ps += __shfl_xor(ps, 32);
    lrun = lrun * corr + ps;

    // ---- P' = p*vs in named registers (static indexing) ----
    float pp0[4], pp1[4], pp2[4], pp3[4], pp4[4], pp5[4], pp6[4], pp7[4];
    #pragma unroll
    for (int rr = 0; rr < 4; ++rr) {
      pp0[rr] = p[0][rr] * vsv4[0][rr];
      pp1[rr] = p[1][rr] * vsv4[1][rr];
      pp2[rr] = p[2][rr] * vsv4[2][rr];
      pp3[rr] = p[3][rr] * vsv4[3][rr];
      pp4[rr] = p[4][rr] * vsv4[4][rr];
      pp5[rr] = p[5][rr] * vsv4[5][rr];
      pp6[rr] = p[6][rr] * vsv4[6][rr];
      pp7[rr] = p[7][rr] * vsv4[7][rr];
    }

    if (!defer) {
      #pragma unroll
      for (int dt = 0; dt < 8; ++dt)
        #pragma unroll
        for (int rr = 0; rr < 4; ++rr) acc_o[dt][rr] *= corr;
    }

    // ---- in-register P redistribution (r17-verified mapping, kb=0..3):
    // dest (lg,lh), frag kb, elem j needs pp[2kb+(lh>>1)][j&3] from lane
    // lg + 16*(2*(lh&1) + (j>>2)).
    int srcA = lg + ((l & 16) << 1);   // lg + 32*(lh&1)
    int srcB = srcA + 16;
    bool hiT = (lh >= 2);
    s16x8 pahi[4], palo[4];
    #pragma unroll
    for (int kb = 0; kb < 4; ++kb) {
      float xv[8];
      #pragma unroll
      for (int rr = 0; rr < 4; ++rr) {
        float se = (kb == 0) ? pp0[rr] : (kb == 1) ? pp2[rr]
                 : (kb == 2) ? pp4[rr] : pp6[rr];
        float so = (kb == 0) ? pp1[rr] : (kb == 1) ? pp3[rr]
                 : (kb == 2) ? pp5[rr] : pp7[rr];
        float loA = __shfl(se, srcA);
        float hiA = __shfl(so, srcA);
        float loB = __shfl(se, srcB);
        float hiB = __shfl(so, srcB);
        xv[rr]     = hiT ? hiA : loA;
        xv[4 + rr] = hiT ? hiB : loB;
      }
      float lv[8];
      #pragma unroll
      for (int jv = 0; jv < 8; ++jv) {
        uint32_t hb = fbits(xv[jv]) & 0xffff0000u;
        union { uint32_t u; float f; } hf; hf.u = hb;
        lv[jv] = xv[jv] - hf.f;
      }
      union { uint32_t u[4]; s16x8 v; } H, L;
      #pragma unroll
      for (int jj = 0; jj < 4; ++jj) {
        H.u[jj] = (fbits(xv[2*jj]) >> 16) | (fbits(xv[2*jj+1]) & 0xffff0000u);
        L.u[jj] = (fbits(lv[2*jj]) >> 16) | (fbits(lv[2*jj+1]) & 0xffff0000u);
      }
      pahi[kb] = H.v; palo[kb] = L.v;
    }

    __builtin_amdgcn_s_setprio(1);
    #pragma unroll
    for (int dt = 0; dt < 8; ++dt) {
      #pragma unroll
      for (int kb = 0; kb < 4; ++kb) {
        s16x8 vb = *(const s16x8*)&Vt[(16*dt + lg)*136 + kb*32 + lh*8];
        acc_o[dt] = mfma_bf16(vb, pahi[kb], acc_o[dt]);
        acc_o[dt] = mfma_bf16(vb, palo[kb], acc_o[dt]);
      }
    }
    __builtin_amdgcn_s_setprio(0);
  }
#undef ISSUE_LOADS

  if (nc == 1) {
    float invv = 1.0f / lrun;
    size_t base = (size_t)myq*DD + (size_t)h*HD;
    #pragma unroll
    for (int dt = 0; dt < 8; ++dt) {
      f32x4 v;
      #pragma unroll
      for (int rr = 0; rr < 4; ++rr) v[rr] = acc_o[dt][rr] * invv;
      *(f32x4*)&ao[base + 16*dt + 4*lh] = v;
    }
  } else {
    int base = (qb2 <= 11) ? (qb2 - 6)*2 : 12 + (qb2 - 12)*3;
    int slot = h*24 + base + c;
    float* op = (slot < 160) ? (opA + (size_t)slot * 16384)
                             : (opB + (size_t)(slot - 160) * 16384);
    op += (size_t)(16*w + lg) * 128;
    #pragma unroll
    for (int dt = 0; dt < 8; ++dt)
      *(f32x4*)&op[16*dt + 4*lh] = acc_o[dt];
    if (lh == 0) {
      ml[slot*256 + 16*w + lg]       = mrun;
      ml[slot*256 + 128 + 16*w + lg] = lrun;
    }
  }
}

// ---------------------------------------------------------------------------
// Kernel 3b: merge 2-3 partial chunks per (h, qb2>=6) tile -> f32 ao.
// (verified round 17)
// ---------------------------------------------------------------------------
__global__ __launch_bounds__(256)
void merge_kernel(const float* __restrict__ opA, const float* __restrict__ opB,
                  const float* __restrict__ ml,
                  float* __restrict__ ao) {
  int tile = blockIdx.x;            // 0..159
  int h = tile / 10;
  int qb2 = 6 + tile % 10;
  int nc = (qb2 <= 11) ? 2 : 3;
  int sbase = h*24 + ((qb2 <= 11) ? (qb2 - 6)*2 : 12 + (qb2 - 12)*3);

  int tid = threadIdx.x;
  int row = tid >> 1;               // 0..127
  int cseg = (tid & 1) * 64;

  float mv[3], lv[3];
  const float* pp[3];
  #pragma unroll
  for (int i = 0; i < 3; ++i) {
    int slot = sbase + ((i < nc) ? i : 0);
    const float* p = (slot < 160) ? (opA + (size_t)slot * 16384)
                                  : (opB + (size_t)(slot - 160) * 16384);
    pp[i] = p + (size_t)row * 128 + cseg;
    if (i < nc) {
      mv[i] = ml[slot*256 + row];
      lv[i] = ml[slot*256 + 128 + row];
    } else {
      mv[i] = -1e30f;
      lv[i] = 0.f;
    }
  }
  float M = fmaxf(fmaxf(mv[0], mv[1]), mv[2]);
  float wgt[3];
  float L = 0.f;
  #pragma unroll
  for (int i = 0; i < 3; ++i) { wgt[i] = EXP2(mv[i] - M); L += wgt[i]*lv[i]; }
  float inv = 1.0f / L;

  size_t ob = (size_t)(qb2*128 + row)*DD + (size_t)h*HD + cseg;
  #pragma unroll
  for (int c4 = 0; c4 < 16; ++c4) {
    f32x4 a0 = *(const f32x4*)&pp[0][c4*4];
    f32x4 a1 = *(const f32x4*)&pp[1][c4*4];
    f32x4 a2 = *(const f32x4*)&pp[2][c4*4];
    f32x4 v;
    #pragma unroll
    for (int e = 0; e < 4; ++e)
      v[e] = (wgt[0]*a0[e] + wgt[1]*a1[e] + wgt[2]*a2[e]) * inv;
    *(f32x4*)&ao[ob + c4*4] = v;
  }
}

// ---------------------------------------------------------------------------
// Kernel 3c: fused rowwise 15-bit digit quantization of ao AND wo.
// (verified round 18)
// ---------------------------------------------------------------------------
__global__ __launch_bounds__(256)
void awquant_kernel(const float* __restrict__ ao, const float* __restrict__ wom,
                    int8_t* __restrict__ ahi, int8_t* __restrict__ alo,
                    int8_t* __restrict__ bhi, int8_t* __restrict__ blo,
                    float* __restrict__ sa, float* __restrict__ sb) {
  int r = blockIdx.x;
  int tid = threadIdx.x;
  const float* src; int8_t* dhi; int8_t* dlo; float* sc; int row;
  if (r < 2048) { src = ao;  dhi = ahi; dlo = alo; sc = sa; row = r; }
  else          { src = wom; dhi = bhi; dlo = blo; sc = sb; row = r - 2048; }
  src += (size_t)row * DD;
  float4 a = ((const float4*)src)[2*tid];
  float4 b = ((const float4*)src)[2*tid+1];
  float v[8] = {a.x, a.y, a.z, a.w, b.x, b.y, b.z, b.w};
  float m = fabsf(v[0]);
  #pragma unroll
  for (int j = 1; j < 8; ++j) m = fmaxf(m, fabsf(v[j]));
  #pragma unroll
  for (int off = 1; off < 64; off <<= 1) m = fmaxf(m, __shfl_xor(m, off));
  __shared__ float wmax[4];
  if ((tid & 63) == 0) wmax[tid >> 6] = m;
  __syncthreads();
  m = fmaxf(fmaxf(wmax[0], wmax[1]), fmaxf(wmax[2], wmax[3]));
  float s = fmaxf(m * (1.0f/16256.0f), 1e-30f);
  if (tid == 0) sc[row] = s;
  float inv = 1.0f / s;
  uint32_t h0 = 0, h1 = 0, l0 = 0, l1 = 0;
  #pragma unroll
  for (int j = 0; j < 8; ++j) {
    float q = v[j] * inv;
    int hi = (int)fminf(fmaxf(rintf(q * (1.0f/128.0f)), -127.0f), 127.0f);
    int lo = (int)fminf(fmaxf(rintf(q - 128.0f*(float)hi), -127.0f), 127.0f);
    if (j < 4) { h0 |= ((uint32_t)hi & 0xffu) << (8*j);     l0 |= ((uint32_t)lo & 0xffu) << (8*j); }
    else       { h1 |= ((uint32_t)hi & 0xffu) << (8*(j-4)); l1 |= ((uint32_t)lo & 0xffu) << (8*(j-4)); }
  }
  ((uint2*)&dhi[(size_t)row*DD])[tid] = make_uint2(h0, h1);
  ((uint2*)&dlo[(size_t)row*DD])[tid] = make_uint2(l0, l1);
}

// ---------------------------------------------------------------------------
// Kernel 4: wo GEMM on int8-digit MFMA (verified rounds 16/18):
// tile 64t x 128o, grid 512, 2 blocks/CU, 1-deep prefetch, XCD map.
// ---------------------------------------------------------------------------
__global__ __launch_bounds__(256)
void wo_gemm_kernel(const int8_t* __restrict__ ahi, const int8_t* __restrict__ alo,
                    const int8_t* __restrict__ bhi, const int8_t* __restrict__ blo,
                    const float* __restrict__ sa, const float* __restrict__ sb,
                    float* __restrict__ outp) {
  int id  = blockIdx.x;           // 0..511
  int xcd = id & 7;
  int j   = id >> 3;              // 0..63
  int tb  = xcd*4 + (j >> 4);     // 0..31
  int ob  = j & 15;               // 0..15
  int t0  = tb * 64;
  int o0  = ob * 128;

  __shared__ int8_t AH[64 * 72];
  __shared__ int8_t AL[64 * 72];
  __shared__ int8_t BH[128 * 72];
  __shared__ int8_t BL[128 * 72];
  int tid = threadIdx.x;
  int wv4 = tid >> 6;
  int wr = wv4 >> 1, wc = wv4 & 1;   // wave tile: 32t x 64o
  int l  = tid & 63;
  int lg = l & 15;
  int lh = l >> 4;

  i32x4 acc_h[2][4], acc_m[2][4];
  #pragma unroll
  for (int ti = 0; ti < 2; ++ti)
    #pragma unroll
    for (int tj = 0; tj < 4; ++tj) {
      acc_h[ti][tj] = (i32x4){0,0,0,0};
      acc_m[ti][tj] = (i32x4){0,0,0,0};
    }

  i32x4 pAH, pAL, pBH[2], pBL[2];
  int ar = tid >> 2, ac = tid & 3;   // A: row 0..63, 16B col chunk 0..3

#define WO_ISSUE(KT)                                                            \
  {                                                                             \
    int k0 = (KT) * 64;                                                         \
    size_t ga = (size_t)(t0 + ar)*DD + k0 + ac*16;                              \
    pAH = *(const i32x4*)&ahi[ga];                                              \
    pAL = *(const i32x4*)&alo[ga];                                              \
    _Pragma("unroll")                                                           \
    for (int i = 0; i < 2; ++i) {                                               \
      int idx = tid + i*256, r = idx >> 2, c = idx & 3;                         \
      size_t gb = (size_t)(o0 + r)*DD + k0 + c*16;                              \
      pBH[i] = *(const i32x4*)&bhi[gb];                                         \
      pBL[i] = *(const i32x4*)&blo[gb];                                         \
    }                                                                           \
  }

  WO_ISSUE(0);

  for (int kt = 0; kt < DD/64; ++kt) {
    __syncthreads();
    *(i32x4*)&AH[ar*72 + ac*16] = pAH;
    *(i32x4*)&AL[ar*72 + ac*16] = pAL;
    #pragma unroll
    for (int i = 0; i < 2; ++i) {
      int idx = tid + i*256, r = idx >> 2, c = idx & 3;
      *(i32x4*)&BH[r*72 + c*16] = pBH[i];
      *(i32x4*)&BL[r*72 + c*16] = pBL[i];
    }
    __syncthreads();
    if (kt + 1 < DD/64) WO_ISSUE(kt + 1);

    i32x4 a_h[2], a_l[2];
    #pragma unroll
    for (int ti = 0; ti < 2; ++ti) {
      int ab = (wr*32 + ti*16 + lg)*72 + lh*16;
      a_h[ti] = *(const i32x4*)&AH[ab];
      a_l[ti] = *(const i32x4*)&AL[ab];
    }
    __builtin_amdgcn_s_setprio(1);
    #pragma unroll
    for (int tj = 0; tj < 4; ++tj) {
      int bb = (wc*64 + tj*16 + lg)*72 + lh*16;
      i32x4 b_h = *(const i32x4*)&BH[bb];
      i32x4 b_l = *(const i32x4*)&BL[bb];
      #pragma unroll
      for (int ti = 0; ti < 2; ++ti) {
        acc_h[ti][tj] = mfma_i8(a_h[ti], b_h, acc_h[ti][tj]);
        acc_m[ti][tj] = mfma_i8(a_h[ti], b_l, acc_m[ti][tj]);
        acc_m[ti][tj] = mfma_i8(a_l[ti], b_h, acc_m[ti][tj]);
      }
    }
    __builtin_amdgcn_s_setprio(0);
  }
#undef WO_ISSUE

  #pragma unroll
  for (int ti = 0; ti < 2; ++ti) {
    float sav[4];
    #pragma unroll
    for (int rr = 0; rr < 4; ++rr)
      sav[rr] = sa[t0 + wr*32 + ti*16 + lh*4 + rr];
    #pragma unroll
    for (int tj = 0; tj < 4; ++tj) {
      int o = o0 + wc*64 + tj*16 + lg;
      float sbo = sb[o];
      #pragma unroll
      for (int rr = 0; rr < 4; ++rr) {
        int t = t0 + wr*32 + ti*16 + lh*4 + rr;
        float v = sav[rr] * sbo *
                  (16384.0f * (float)acc_h[ti][tj][rr] + 128.0f * (float)acc_m[ti][tj][rr]);
        outp[(size_t)t*DD + o] = v;
      }
    }
  }
}

// ---------------------------------------------------------------------------
extern "C" void kernel_launch(void* const* d_in, const int* in_sizes, int n_in,
                              void* d_out, int out_size, void* d_ws, size_t ws_size,
                              hipStream_t stream) {
  (void)in_sizes; (void)n_in; (void)out_size; (void)ws_size;
  const float* x  = (const float*)d_in[0];
  const float* wq = (const float*)d_in[1];
  const float* wk = (const float*)d_in[2];
  const float* wv = (const float*)d_in[3];
  const float* wo = (const float*)d_in[4];
  float* out = (float*)d_out;

  char* ws = (char*)d_ws;
  const size_t MB = 1048576;
  int8_t* qx  = (int8_t*)(ws);           // dead after proj
  int8_t* qwq = (int8_t*)(ws + 4*MB);    // dead after proj
  int8_t* qwk = (int8_t*)(ws + 8*MB);    // dead after proj
  int8_t* qwv = (int8_t*)(ws + 9*MB);    // dead after proj
  int8_t* qqp = (int8_t*)(ws + 10*MB);   // [16][2048][128]; live during attn
  int8_t* kqp = (int8_t*)(ws + 14*MB);   // [4][2048][128];  live during attn
  int8_t* vqp = (int8_t*)(ws + 15*MB);   // [4][2048][128];  live during attn
  float* xs  = (float*)(ws + 16*MB);
  float* wqs = xs + 2048;
  float* wks = wqs + 2048;
  float* wvs = wks + 512;
  float* qsc = wvs + 512;
  float* ksc = qsc + (size_t)NH*TT;
  float* vsc = ksc + (size_t)NKV*TT;
  // f32 ao [2048][2048]: 16 MB at ws+16.25MB.
  float* ao = (float*)(ws + 16*MB + 262144);
  // RoPE table: 1 MB over ao region (dead after proj; ao written by attn).
  float2* ropet = (float2*)(ws + 16*MB + 262144);
  // attn partial slots (64 KB each): slots 0..159 in ws[0..10MB); slots
  // 160..383 in d_out[0..14MB); m/l at d_out+15.5MB. All dead after merge.
  float* opA = (float*)(ws);
  float* opB = out;
  float* mlb = (float*)((char*)out + 15*MB + 524288);
  // digit-GEMM buffers (after merge, ws[0..16MB) and scale region dead):
  int8_t* ahi = (int8_t*)(ws);
  int8_t* alo = (int8_t*)(ws + 4*MB);
  int8_t* bhi = (int8_t*)(ws + 8*MB);
  int8_t* blo = (int8_t*)(ws + 12*MB);
  float* sa = (float*)(ws + 16*MB);
  float* sb = sa + 2048;

  quant_rows_kernel<<<5632, 256, 0, stream>>>(x, wq, wk, wv,
                                              qx, xs, qwq, wqs, qwk, wks, qwv, wvs,
                                              ropet);
  proj_kernel<<<768, 256, 0, stream>>>(
      qx, xs, qwq, wqs, qwk, wks, qwv, wvs, ropet,
      qqp, qsc, kqp, ksc, vqp, vsc);
  attn_mfma_kernel<<<480, 512, 0, stream>>>(
      qqp, qsc, kqp, ksc, vqp, vsc, ao, opA, opB, mlb);
  merge_kernel<<<160, 256, 0, stream>>>(opA, opB, mlb, ao);
  awquant_kernel<<<4096, 256, 0, stream>>>(ao, wo, ahi, alo, bhi, blo, sa, sb);
  wo_gemm_kernel<<<512, 256, 0, stream>>>(ahi, alo, bhi, blo, sa, sb, out);
}

// Round 22
// 150.557 us; speedup vs baseline: 1.0897x; 1.0897x over previous
//
#include <hip/hip_runtime.h>
#include <cstdint>
#include <math.h>

#define TT 2048
#define DD 2048
#define NH 16
#define NKV 4
#define HD 128
#define SCALE_F 0.08838834764831845f
#define LOG2E 1.4426950408889634f

#if __has_builtin(__builtin_amdgcn_exp2f)
#define EXP2(x) __builtin_amdgcn_exp2f(x)
#else
#define EXP2(x) exp2f(x)
#endif

typedef int   i32x4 __attribute__((ext_vector_type(4)));
typedef float f32x4 __attribute__((ext_vector_type(4)));
typedef short s16x8 __attribute__((ext_vector_type(8)));

__device__ __forceinline__ i32x4 mfma_i8(i32x4 a, i32x4 b, i32x4 c) {
  return __builtin_amdgcn_mfma_i32_16x16x64_i8(a, b, c, 0, 0, 0);
}
__device__ __forceinline__ f32x4 mfma_bf16(s16x8 a, s16x8 b, f32x4 c) {
  return __builtin_amdgcn_mfma_f32_16x16x32_bf16(a, b, c, 0, 0, 0);
}
__device__ __forceinline__ uint32_t fbits(float f) {
  union { float f; uint32_t u; } x; x.f = f; return x.u;
}
__device__ __forceinline__ float bf16_to_f(ushort h) {
  union { uint32_t u; float f; } x; x.u = ((uint32_t)h) << 16; return x.f;
}

// ---------------------------------------------------------------------------
// Kernel 1: rowwise int8 quantization for x/wq/wk/wv + fused RoPE table.
// (verified round 18)
// ---------------------------------------------------------------------------
__global__ __launch_bounds__(256)
void quant_rows_kernel(const float* __restrict__ x, const float* __restrict__ wq,
                       const float* __restrict__ wk, const float* __restrict__ wv,
                       int8_t* __restrict__ qx, float* __restrict__ xs,
                       int8_t* __restrict__ qwq, float* __restrict__ wqs,
                       int8_t* __restrict__ qwk, float* __restrict__ wks,
                       int8_t* __restrict__ qwv, float* __restrict__ wvs,
                       float2* __restrict__ ropet) {
  int r = blockIdx.x;
  int tid = threadIdx.x;
  if (r >= 5120) {                       // RoPE table branch (uniform per block)
    int idx = (r - 5120) * 256 + tid;    // 0..131071
    int t = idx >> 6, d = idx & 63;
    float inv = 1.0f / powf(1000000.0f, (float)d * (1.0f/64.0f));
    float sn, cs;
    sincosf((float)t * inv, &sn, &cs);
    ropet[idx] = make_float2(cs, sn);
    return;
  }
  const float* src; int8_t* dst; float* sc; int row;
  if (r < 2048)      { src = x;  dst = qx;  sc = xs;  row = r; }
  else if (r < 4096) { src = wq; dst = qwq; sc = wqs; row = r - 2048; }
  else if (r < 4608) { src = wk; dst = qwk; sc = wks; row = r - 4096; }
  else               { src = wv; dst = qwv; sc = wvs; row = r - 4608; }
  src += (size_t)row * DD; dst += (size_t)row * DD;
  float4 v0 = ((const float4*)src)[2*tid];
  float4 v1 = ((const float4*)src)[2*tid+1];
  float m = fmaxf(fmaxf(fmaxf(fabsf(v0.x), fabsf(v0.y)), fmaxf(fabsf(v0.z), fabsf(v0.w))),
                  fmaxf(fmaxf(fabsf(v1.x), fabsf(v1.y)), fmaxf(fabsf(v1.z), fabsf(v1.w))));
  #pragma unroll
  for (int off = 1; off < 64; off <<= 1) m = fmaxf(m, __shfl_xor(m, off));
  __shared__ float wmax[4];
  if ((tid & 63) == 0) wmax[tid >> 6] = m;
  __syncthreads();
  m = fmaxf(fmaxf(wmax[0], wmax[1]), fmaxf(wmax[2], wmax[3]));
  float s = fmaxf(m / 127.0f, 1e-8f);
  if (tid == 0) sc[row] = s;
  float vv[8] = {v0.x, v0.y, v0.z, v0.w, v1.x, v1.y, v1.z, v1.w};
  uint32_t p0 = 0, p1 = 0;
  #pragma unroll
  for (int i = 0; i < 4; ++i) {
    int q = (int)fminf(fmaxf(rintf(vv[i] / s), -127.0f), 127.0f);
    p0 |= ((uint32_t)q & 0xffu) << (8*i);
  }
  #pragma unroll
  for (int i = 0; i < 4; ++i) {
    int q = (int)fminf(fmaxf(rintf(vv[4+i] / s), -127.0f), 127.0f);
    p1 |= ((uint32_t)q & 0xffu) << (8*i);
  }
  ((uint2*)dst)[tid] = make_uint2(p0, p1);
}

// ---------------------------------------------------------------------------
// Kernel 2: i8-MFMA projection GEMM + dequant + RoPE(table) + requant.
// (verified round 18: 4 waves, wave owns 16 t-rows x 128 o-cols)
// ---------------------------------------------------------------------------
__global__ __launch_bounds__(256)
void proj_kernel(const int8_t* __restrict__ qx, const float* __restrict__ xs,
                 const int8_t* __restrict__ qwq, const float* __restrict__ wqs,
                 const int8_t* __restrict__ qwk, const float* __restrict__ wks,
                 const int8_t* __restrict__ qwv, const float* __restrict__ wvs,
                 const float2* __restrict__ ropet,
                 int8_t* __restrict__ qq, float* __restrict__ qsc_out,
                 int8_t* __restrict__ kq, float* __restrict__ ksc_out,
                 int8_t* __restrict__ vq, float* __restrict__ vsc_out) {
  int id  = blockIdx.x;          // 0..767
  int xcd = id & 7;
  int j   = id >> 3;             // 0..95
  int hg  = xcd >> 1;
  int th  = xcd & 1;
  int gh  = hg*6 + (j % 6);      // 0..23
  int tb  = th*16 + (j / 6);     // 0..31
  int t0  = tb * 64;

  const int8_t* wgt; const float* wsc; int8_t* outq; float* outs; bool doRope;
  if (gh < NH) {
    wgt = qwq + (size_t)gh*HD*DD; wsc = wqs + gh*HD;
    outq = qq + (size_t)gh*TT*HD; outs = qsc_out + (size_t)gh*TT; doRope = true;
  } else if (gh < NH + NKV) {
    int hh = gh - NH;
    wgt = qwk + (size_t)hh*HD*DD; wsc = wks + hh*HD;
    outq = kq + (size_t)hh*TT*HD; outs = ksc_out + (size_t)hh*TT; doRope = true;
  } else {
    int hh = gh - NH - NKV;
    wgt = qwv + (size_t)hh*HD*DD; wsc = wvs + hh*HD;
    outq = vq + (size_t)hh*TT*HD; outs = vsc_out + (size_t)hh*TT; doRope = false;
  }

  __shared__ int8_t As[64 * 144];
  __shared__ int8_t Bs[128 * 144];
  int tid = threadIdx.x;
  int w  = tid >> 6;    // wave 0..3: t rows w*16 .. +15
  int l  = tid & 63;
  int lg = l & 15;
  int lh = l >> 4;

  i32x4 acc[8];
  #pragma unroll
  for (int tj = 0; tj < 8; ++tj) acc[tj] = (i32x4){0,0,0,0};

  i32x4 prefA[2], prefB[4];

#define PROJ_ISSUE(KT)                                                          \
  {                                                                             \
    int kk0 = (KT) * 128;                                                       \
    _Pragma("unroll")                                                           \
    for (int i = 0; i < 2; ++i) {                                               \
      int idx = tid + i*256, r = idx >> 3, c = idx & 7;                         \
      prefA[i] = *(const i32x4*)&qx[(size_t)(t0 + r)*DD + kk0 + c*16];          \
    }                                                                           \
    _Pragma("unroll")                                                           \
    for (int i = 0; i < 4; ++i) {                                               \
      int idx = tid + i*256, r = idx >> 3, c = idx & 7;                         \
      prefB[i] = *(const i32x4*)&wgt[(size_t)r*DD + kk0 + c*16];                \
    }                                                                           \
  }

  PROJ_ISSUE(0);

  for (int kt = 0; kt < DD/128; ++kt) {
    __syncthreads();
    #pragma unroll
    for (int i = 0; i < 2; ++i) {
      int idx = tid + i*256, r = idx >> 3, c = idx & 7;
      *(i32x4*)&As[r*144 + c*16] = prefA[i];
    }
    #pragma unroll
    for (int i = 0; i < 4; ++i) {
      int idx = tid + i*256, r = idx >> 3, c = idx & 7;
      *(i32x4*)&Bs[r*144 + c*16] = prefB[i];
    }
    __syncthreads();
    if (kt + 1 < DD/128) PROJ_ISSUE(kt + 1);

    #pragma unroll
    for (int s = 0; s < 2; ++s) {
      i32x4 a0 = *(const i32x4*)&As[(w*16 + lg)*144 + s*64 + lh*16];
      #pragma unroll
      for (int tj = 0; tj < 8; ++tj) {
        i32x4 b = *(const i32x4*)&Bs[(tj*16 + lg)*144 + s*64 + lh*16];
        acc[tj] = mfma_i8(a0, b, acc[tj]);
      }
    }
  }
#undef PROJ_ISSUE

  float y[8][4];
  #pragma unroll
  for (int rr = 0; rr < 4; ++rr) {
    int tl = w*16 + lh*4 + rr;
    float xsi = xs[t0 + tl];
    #pragma unroll
    for (int tj = 0; tj < 8; ++tj)
      y[tj][rr] = (float)acc[tj][rr] * xsi * wsc[tj*16 + lg];
  }

  if (doRope) {
    #pragma unroll
    for (int rr = 0; rr < 4; ++rr) {
      int trow = t0 + w*16 + lh*4 + rr;
      const float2* tr = &ropet[trow * 64];
      #pragma unroll
      for (int tj = 0; tj < 4; ++tj) {
        float2 cssn = tr[tj*16 + lg];
        float lo = y[tj][rr], hi = y[tj+4][rr];
        y[tj][rr]   = lo*cssn.x - hi*cssn.y;
        y[tj+4][rr] = hi*cssn.x + lo*cssn.y;
      }
    }
  }

  __syncthreads();
  #pragma unroll
  for (int rr = 0; rr < 4; ++rr) {
    int tl = w*16 + lh*4 + rr;
    float mx = fabsf(y[0][rr]);
    #pragma unroll
    for (int tj = 1; tj < 8; ++tj) mx = fmaxf(mx, fabsf(y[tj][rr]));
    mx = fmaxf(mx, __shfl_xor(mx, 1));
    mx = fmaxf(mx, __shfl_xor(mx, 2));
    mx = fmaxf(mx, __shfl_xor(mx, 4));
    mx = fmaxf(mx, __shfl_xor(mx, 8));
    float s = fmaxf(mx / 127.0f, 1e-8f);
    if (lg == 0) outs[t0 + tl] = s;
    #pragma unroll
    for (int tj = 0; tj < 8; ++tj) {
      int qv = (int)fminf(fmaxf(rintf(y[tj][rr] / s), -127.0f), 127.0f);
      As[tl*144 + tj*16 + lg] = (int8_t)qv;
    }
  }
  __syncthreads();
  #pragma unroll
  for (int i = 0; i < 2; ++i) {
    int idx = tid + i*256, r = idx >> 3, c = idx & 7;
    *(i32x4*)&outq[(size_t)(t0 + r)*HD + c*16] = *(const i32x4*)&As[r*144 + c*16];
  }
}

// ---------------------------------------------------------------------------
// Kernel 3: MFMA flash attention, balanced chunked K + T13 defer-max.
// (verified rounds 19/20 — KB=64 body)
// ---------------------------------------------------------------------------
__global__ __launch_bounds__(512)
void attn_mfma_kernel(const int8_t* __restrict__ qq, const float* __restrict__ qsc_in,
                      const int8_t* __restrict__ kq, const float* __restrict__ ksc_in,
                      const int8_t* __restrict__ vq, const float* __restrict__ vsc_in,
                      float* __restrict__ ao,
                      float* __restrict__ opA, float* __restrict__ opB,
                      float* __restrict__ ml) {
  int id = blockIdx.x;              // 0..479
  int h   = id / 30;
  int loc = id % 30;
  int qb2, c;
  if (loc < 12)      { qb2 = 15 - loc/3;        c = loc % 3; }
  else if (loc < 24) { qb2 = 11 - (loc - 12)/2; c = (loc - 12) % 2; }
  else               { qb2 = 5 - (loc - 24);    c = 0; }
  int nkt = 2*qb2 + 2;
  int nc  = (qb2 <= 5) ? 1 : ((qb2 <= 11) ? 2 : 3);
  int ktb = (c * nkt) / nc;
  int kte = ((c + 1) * nkt) / nc;
  int hk  = h >> 2;
  int qb0 = qb2 * 128;

  __shared__ int8_t Ks[64 * 144];
  __shared__ ushort Vt[128 * 72];
  __shared__ float  Pf[8][16 * 68];

  int tid = threadIdx.x;
  int w  = tid >> 6;    // 0..7
  int l  = tid & 63;
  int lg = l & 15;
  int lh = l >> 4;

  const int8_t* qp = &qq[((size_t)h*TT + qb0 + 16*w + lg)*HD + lh*16];
  i32x4 qa0 = *(const i32x4*)qp;
  i32x4 qa1 = *(const i32x4*)(qp + 64);

  int myq = qb0 + 16*w + lg;
  float qsl = qsc_in[(size_t)h*TT + myq] * (SCALE_F * LOG2E);

  float mrun = -1e30f, lrun = 0.f;
  f32x4 acc_o[8];
  #pragma unroll
  for (int dt = 0; dt < 8; ++dt) acc_o[dt] = (f32x4){0.f, 0.f, 0.f, 0.f};

  int sr = tid >> 3, scc = tid & 7;           // K: row 0..63, col 0..7
  int m2 = tid & 31, d0 = (tid >> 5) * 8;     // V: k-pair 2*m2, d0 0..120

  i32x4 kreg;
  int2  vreg0, vreg1;

#define ISSUE_LOADS(KT)                                                         \
  {                                                                             \
    int kk0 = (KT) * 64;                                                        \
    kreg = *(const i32x4*)&kq[((size_t)hk*TT + kk0 + sr)*HD + scc*16];          \
    const int8_t* vp = &vq[((size_t)hk*TT + kk0 + 2*m2)*HD + d0];               \
    vreg0 = *(const int2*)vp;                                                   \
    vreg1 = *(const int2*)(vp + HD);                                            \
  }

  ISSUE_LOADS(ktb);

  for (int kt = ktb; kt < kte; ++kt) {
    int k0 = kt * 64;
    __syncthreads();
    *(i32x4*)&Ks[sr*144 + scc*16] = kreg;
    #pragma unroll
    for (int jj = 0; jj < 4; ++jj) {
      int a0 = (vreg0.x << (24 - 8*jj)) >> 24;
      int b0 = (vreg1.x << (24 - 8*jj)) >> 24;
      *(uint32_t*)&Vt[(d0 + jj)*72 + 2*m2] =
          (fbits((float)a0) >> 16) | ((fbits((float)b0) >> 16) << 16);
      int a1 = (vreg0.y << (24 - 8*jj)) >> 24;
      int b1 = (vreg1.y << (24 - 8*jj)) >> 24;
      *(uint32_t*)&Vt[(d0 + 4 + jj)*72 + 2*m2] =
          (fbits((float)a1) >> 16) | ((fbits((float)b1) >> 16) << 16);
    }
    __syncthreads();
    if (kt + 1 < kte) ISSUE_LOADS(kt + 1);

    i32x4 sacc[4];
    #pragma unroll
    for (int t = 0; t < 4; ++t) sacc[t] = (i32x4){0, 0, 0, 0};
    __builtin_amdgcn_s_setprio(1);
    #pragma unroll
    for (int t = 0; t < 4; ++t) {
      const int8_t* kp = &Ks[(16*t + lg)*144 + lh*16];
      i32x4 b0 = *(const i32x4*)kp;
      i32x4 b1 = *(const i32x4*)(kp + 64);
      sacc[t] = mfma_i8(b0, qa0, sacc[t]);
      sacc[t] = mfma_i8(b1, qa1, sacc[t]);
    }
    __builtin_amdgcn_s_setprio(0);

    f32x4 ksv4[4], vsv4[4];
    #pragma unroll
    for (int t = 0; t < 4; ++t) {
      ksv4[t] = *(const f32x4*)&ksc_in[(size_t)hk*TT + k0 + 16*t + 4*lh];
      vsv4[t] = *(const f32x4*)&vsc_in[(size_t)hk*TT + k0 + 16*t + 4*lh];
    }

    bool maskTile = (kt >= nkt - 2);
    float sf[4][4];
    #pragma unroll
    for (int t = 0; t < 4; ++t)
      #pragma unroll
      for (int rr = 0; rr < 4; ++rr) {
        float v = (float)sacc[t][rr] * qsl * ksv4[t][rr];
        if (maskTile) {
          int kkg = k0 + 16*t + 4*lh + rr;
          v = (kkg <= myq) ? v : -1e30f;
        }
        sf[t][rr] = v;
      }

    float rm = sf[0][0];
    #pragma unroll
    for (int t = 0; t < 4; ++t)
      #pragma unroll
      for (int rr = 0; rr < 4; ++rr) rm = fmaxf(rm, sf[t][rr]);
    rm = fmaxf(rm, __shfl_xor(rm, 16));
    rm = fmaxf(rm, __shfl_xor(rm, 32));

    // T13 defer-max: keep old max when tile max is within 8 (log2 domain)
    bool defer = __all(rm <= mrun + 8.0f && mrun > -1e29f);
    float mnew, corr;
    if (defer) { mnew = mrun; corr = 1.0f; }
    else       { mnew = fmaxf(mrun, rm); corr = EXP2(mrun - mnew); mrun = mnew; }

    float p[4][4];
    float ps = 0.f;
    #pragma unroll
    for (int t = 0; t < 4; ++t)
      #pragma unroll
      for (int rr = 0; rr < 4; ++rr) { p[t][rr] = EXP2(sf[t][rr] - mnew); ps += p[t][rr]; }
    ps += __shfl_xor(ps, 16);
    ps += __shfl_xor(ps, 32);
    lrun = lrun * corr + ps;

    #pragma unroll
    for (int t = 0; t < 4; ++t) {
      f32x4 pw;
      #pragma unroll
      for (int rr = 0; rr < 4; ++rr) pw[rr] = p[t][rr] * vsv4[t][rr];
      *(f32x4*)&Pf[w][lg*68 + 16*t + 4*lh] = pw;
    }

    if (!defer) {
      #pragma unroll
      for (int dt = 0; dt < 8; ++dt)
        #pragma unroll
        for (int rr = 0; rr < 4; ++rr) acc_o[dt][rr] *= corr;
    }

    s16x8 pahi[2], palo[2];
    #pragma unroll
    for (int kb = 0; kb < 2; ++kb) {
      const float* pr = &Pf[w][lg*68 + kb*32 + lh*8];
      f32x4 x0 = *(const f32x4*)pr;
      f32x4 x1 = *(const f32x4*)(pr + 4);
      float xv[8] = {x0.x, x0.y, x0.z, x0.w, x1.x, x1.y, x1.z, x1.w};
      float lv[8];
      #pragma unroll
      for (int jv = 0; jv < 8; ++jv) {
        uint32_t hb = fbits(xv[jv]) & 0xffff0000u;
        union { uint32_t u; float f; } hf; hf.u = hb;
        lv[jv] = xv[jv] - hf.f;
      }
      union { uint32_t u[4]; s16x8 v; } H, L;
      #pragma unroll
      for (int jj = 0; jj < 4; ++jj) {
        H.u[jj] = (fbits(xv[2*jj]) >> 16) | (fbits(xv[2*jj+1]) & 0xffff0000u);
        L.u[jj] = (fbits(lv[2*jj]) >> 16) | (fbits(lv[2*jj+1]) & 0xffff0000u);
      }
      pahi[kb] = H.v; palo[kb] = L.v;
    }

    __builtin_amdgcn_s_setprio(1);
    #pragma unroll
    for (int dt = 0; dt < 8; ++dt) {
      #pragma unroll
      for (int kb = 0; kb < 2; ++kb) {
        s16x8 vb = *(const s16x8*)&Vt[(16*dt + lg)*72 + kb*32 + lh*8];
        acc_o[dt] = mfma_bf16(vb, pahi[kb], acc_o[dt]);
        acc_o[dt] = mfma_bf16(vb, palo[kb], acc_o[dt]);
      }
    }
    __builtin_amdgcn_s_setprio(0);
  }
#undef ISSUE_LOADS

  if (nc == 1) {
    float invv = 1.0f / lrun;
    size_t base = (size_t)myq*DD + (size_t)h*HD;
    #pragma unroll
    for (int dt = 0; dt < 8; ++dt) {
      f32x4 v;
      #pragma unroll
      for (int rr = 0; rr < 4; ++rr) v[rr] = acc_o[dt][rr] * invv;
      *(f32x4*)&ao[base + 16*dt + 4*lh] = v;
    }
  } else {
    int base = (qb2 <= 11) ? (qb2 - 6)*2 : 12 + (qb2 - 12)*3;
    int slot = h*24 + base + c;
    float* op = (slot < 160) ? (opA + (size_t)slot * 16384)
                             : (opB + (size_t)(slot - 160) * 16384);
    op += (size_t)(16*w + lg) * 128;
    #pragma unroll
    for (int dt = 0; dt < 8; ++dt)
      *(f32x4*)&op[16*dt + 4*lh] = acc_o[dt];
    if (lh == 0) {
      ml[slot*256 + 16*w + lg]       = mrun;
      ml[slot*256 + 128 + 16*w + lg] = lrun;
    }
  }
}

// ---------------------------------------------------------------------------
// Kernel 3b: merge 2-3 partial chunks per (h, qb2>=6) tile -> f32 ao.
// (verified round 17)
// ---------------------------------------------------------------------------
__global__ __launch_bounds__(256)
void merge_kernel(const float* __restrict__ opA, const float* __restrict__ opB,
                  const float* __restrict__ ml,
                  float* __restrict__ ao) {
  int tile = blockIdx.x;            // 0..159
  int h = tile / 10;
  int qb2 = 6 + tile % 10;
  int nc = (qb2 <= 11) ? 2 : 3;
  int sbase = h*24 + ((qb2 <= 11) ? (qb2 - 6)*2 : 12 + (qb2 - 12)*3);

  int tid = threadIdx.x;
  int row = tid >> 1;               // 0..127
  int cseg = (tid & 1) * 64;

  float mv[3], lv[3];
  const float* pp[3];
  #pragma unroll
  for (int i = 0; i < 3; ++i) {
    int slot = sbase + ((i < nc) ? i : 0);
    const float* p = (slot < 160) ? (opA + (size_t)slot * 16384)
                                  : (opB + (size_t)(slot - 160) * 16384);
    pp[i] = p + (size_t)row * 128 + cseg;
    if (i < nc) {
      mv[i] = ml[slot*256 + row];
      lv[i] = ml[slot*256 + 128 + row];
    } else {
      mv[i] = -1e30f;
      lv[i] = 0.f;
    }
  }
  float M = fmaxf(fmaxf(mv[0], mv[1]), mv[2]);
  float wgt[3];
  float L = 0.f;
  #pragma unroll
  for (int i = 0; i < 3; ++i) { wgt[i] = EXP2(mv[i] - M); L += wgt[i]*lv[i]; }
  float inv = 1.0f / L;

  size_t ob = (size_t)(qb2*128 + row)*DD + (size_t)h*HD + cseg;
  #pragma unroll
  for (int c4 = 0; c4 < 16; ++c4) {
    f32x4 a0 = *(const f32x4*)&pp[0][c4*4];
    f32x4 a1 = *(const f32x4*)&pp[1][c4*4];
    f32x4 a2 = *(const f32x4*)&pp[2][c4*4];
    f32x4 v;
    #pragma unroll
    for (int e = 0; e < 4; ++e)
      v[e] = (wgt[0]*a0[e] + wgt[1]*a1[e] + wgt[2]*a2[e]) * inv;
    *(f32x4*)&ao[ob + c4*4] = v;
  }
}

// ---------------------------------------------------------------------------
// Kernel 3c: fused rowwise 15-bit digit quantization of ao AND wo.
// (verified round 18)
// ---------------------------------------------------------------------------
__global__ __launch_bounds__(256)
void awquant_kernel(const float* __restrict__ ao, const float* __restrict__ wom,
                    int8_t* __restrict__ ahi, int8_t* __restrict__ alo,
                    int8_t* __restrict__ bhi, int8_t* __restrict__ blo,
                    float* __restrict__ sa, float* __restrict__ sb) {
  int r = blockIdx.x;
  int tid = threadIdx.x;
  const float* src; int8_t* dhi; int8_t* dlo; float* sc; int row;
  if (r < 2048) { src = ao;  dhi = ahi; dlo = alo; sc = sa; row = r; }
  else          { src = wom; dhi = bhi; dlo = blo; sc = sb; row = r - 2048; }
  src += (size_t)row * DD;
  float4 a = ((const float4*)src)[2*tid];
  float4 b = ((const float4*)src)[2*tid+1];
  float v[8] = {a.x, a.y, a.z, a.w, b.x, b.y, b.z, b.w};
  float m = fabsf(v[0]);
  #pragma unroll
  for (int j = 1; j < 8; ++j) m = fmaxf(m, fabsf(v[j]));
  #pragma unroll
  for (int off = 1; off < 64; off <<= 1) m = fmaxf(m, __shfl_xor(m, off));
  __shared__ float wmax[4];
  if ((tid & 63) == 0) wmax[tid >> 6] = m;
  __syncthreads();
  m = fmaxf(fmaxf(wmax[0], wmax[1]), fmaxf(wmax[2], wmax[3]));
  float s = fmaxf(m * (1.0f/16256.0f), 1e-30f);
  if (tid == 0) sc[row] = s;
  float inv = 1.0f / s;
  uint32_t h0 = 0, h1 = 0, l0 = 0, l1 = 0;
  #pragma unroll
  for (int j = 0; j < 8; ++j) {
    float q = v[j] * inv;
    int hi = (int)fminf(fmaxf(rintf(q * (1.0f/128.0f)), -127.0f), 127.0f);
    int lo = (int)fminf(fmaxf(rintf(q - 128.0f*(float)hi), -127.0f), 127.0f);
    if (j < 4) { h0 |= ((uint32_t)hi & 0xffu) << (8*j);     l0 |= ((uint32_t)lo & 0xffu) << (8*j); }
    else       { h1 |= ((uint32_t)hi & 0xffu) << (8*(j-4)); l1 |= ((uint32_t)lo & 0xffu) << (8*(j-4)); }
  }
  ((uint2*)&dhi[(size_t)row*DD])[tid] = make_uint2(h0, h1);
  ((uint2*)&dlo[(size_t)row*DD])[tid] = make_uint2(l0, l1);
}

// ---------------------------------------------------------------------------
// Kernel 4: wo GEMM on int8-digit MFMA (verified rounds 16/18):
// tile 64t x 128o, grid 512, 2 blocks/CU, 1-deep prefetch, XCD map.
// ---------------------------------------------------------------------------
__global__ __launch_bounds__(256)
void wo_gemm_kernel(const int8_t* __restrict__ ahi, const int8_t* __restrict__ alo,
                    const int8_t* __restrict__ bhi, const int8_t* __restrict__ blo,
                    const float* __restrict__ sa, const float* __restrict__ sb,
                    float* __restrict__ outp) {
  int id  = blockIdx.x;           // 0..511
  int xcd = id & 7;
  int j   = id >> 3;              // 0..63
  int tb  = xcd*4 + (j >> 4);     // 0..31
  int ob  = j & 15;               // 0..15
  int t0  = tb * 64;
  int o0  = ob * 128;

  __shared__ int8_t AH[64 * 72];
  __shared__ int8_t AL[64 * 72];
  __shared__ int8_t BH[128 * 72];
  __shared__ int8_t BL[128 * 72];
  int tid = threadIdx.x;
  int wv4 = tid >> 6;
  int wr = wv4 >> 1, wc = wv4 & 1;   // wave tile: 32t x 64o
  int l  = tid & 63;
  int lg = l & 15;
  int lh = l >> 4;

  i32x4 acc_h[2][4], acc_m[2][4];
  #pragma unroll
  for (int ti = 0; ti < 2; ++ti)
    #pragma unroll
    for (int tj = 0; tj < 4; ++tj) {
      acc_h[ti][tj] = (i32x4){0,0,0,0};
      acc_m[ti][tj] = (i32x4){0,0,0,0};
    }

  i32x4 pAH, pAL, pBH[2], pBL[2];
  int ar = tid >> 2, ac = tid & 3;   // A: row 0..63, 16B col chunk 0..3

#define WO_ISSUE(KT)                                                            \
  {                                                                             \
    int k0 = (KT) * 64;                                                         \
    size_t ga = (size_t)(t0 + ar)*DD + k0 + ac*16;                              \
    pAH = *(const i32x4*)&ahi[ga];                                              \
    pAL = *(const i32x4*)&alo[ga];                                              \
    _Pragma("unroll")                                                           \
    for (int i = 0; i < 2; ++i) {                                               \
      int idx = tid + i*256, r = idx >> 2, c = idx & 3;                         \
      size_t gb = (size_t)(o0 + r)*DD + k0 + c*16;                              \
      pBH[i] = *(const i32x4*)&bhi[gb];                                         \
      pBL[i] = *(const i32x4*)&blo[gb];                                         \
    }                                                                           \
  }

  WO_ISSUE(0);

  for (int kt = 0; kt < DD/64; ++kt) {
    __syncthreads();
    *(i32x4*)&AH[ar*72 + ac*16] = pAH;
    *(i32x4*)&AL[ar*72 + ac*16] = pAL;
    #pragma unroll
    for (int i = 0; i < 2; ++i) {
      int idx = tid + i*256, r = idx >> 2, c = idx & 3;
      *(i32x4*)&BH[r*72 + c*16] = pBH[i];
      *(i32x4*)&BL[r*72 + c*16] = pBL[i];
    }
    __syncthreads();
    if (kt + 1 < DD/64) WO_ISSUE(kt + 1);

    i32x4 a_h[2], a_l[2];
    #pragma unroll
    for (int ti = 0; ti < 2; ++ti) {
      int ab = (wr*32 + ti*16 + lg)*72 + lh*16;
      a_h[ti] = *(const i32x4*)&AH[ab];
      a_l[ti] = *(const i32x4*)&AL[ab];
    }
    __builtin_amdgcn_s_setprio(1);
    #pragma unroll
    for (int tj = 0; tj < 4; ++tj) {
      int bb = (wc*64 + tj*16 + lg)*72 + lh*16;
      i32x4 b_h = *(const i32x4*)&BH[bb];
      i32x4 b_l = *(const i32x4*)&BL[bb];
      #pragma unroll
      for (int ti = 0; ti < 2; ++ti) {
        acc_h[ti][tj] = mfma_i8(a_h[ti], b_h, acc_h[ti][tj]);
        acc_m[ti][tj] = mfma_i8(a_h[ti], b_l, acc_m[ti][tj]);
        acc_m[ti][tj] = mfma_i8(a_l[ti], b_h, acc_m[ti][tj]);
      }
    }
    __builtin_amdgcn_s_setprio(0);
  }
#undef WO_ISSUE

  #pragma unroll
  for (int ti = 0; ti < 2; ++ti) {
    float sav[4];
    #pragma unroll
    for (int rr = 0; rr < 4; ++rr)
      sav[rr] = sa[t0 + wr*32 + ti*16 + lh*4 + rr];
    #pragma unroll
    for (int tj = 0; tj < 4; ++tj) {
      int o = o0 + wc*64 + tj*16 + lg;
      float sbo = sb[o];
      #pragma unroll
      for (int rr = 0; rr < 4; ++rr) {
        int t = t0 + wr*32 + ti*16 + lh*4 + rr;
        float v = sav[rr] * sbo *
                  (16384.0f * (float)acc_h[ti][tj][rr] + 128.0f * (float)acc_m[ti][tj][rr]);
        outp[(size_t)t*DD + o] = v;
      }
    }
  }
}

// ---------------------------------------------------------------------------
extern "C" void kernel_launch(void* const* d_in, const int* in_sizes, int n_in,
                              void* d_out, int out_size, void* d_ws, size_t ws_size,
                              hipStream_t stream) {
  (void)in_sizes; (void)n_in; (void)out_size; (void)ws_size;
  const float* x  = (const float*)d_in[0];
  const float* wq = (const float*)d_in[1];
  const float* wk = (const float*)d_in[2];
  const float* wv = (const float*)d_in[3];
  const float* wo = (const float*)d_in[4];
  float* out = (float*)d_out;

  char* ws = (char*)d_ws;
  const size_t MB = 1048576;
  int8_t* qx  = (int8_t*)(ws);           // dead after proj
  int8_t* qwq = (int8_t*)(ws + 4*MB);    // dead after proj
  int8_t* qwk = (int8_t*)(ws + 8*MB);    // dead after proj
  int8_t* qwv = (int8_t*)(ws + 9*MB);    // dead after proj
  int8_t* qqp = (int8_t*)(ws + 10*MB);   // [16][2048][128]; live during attn
  int8_t* kqp = (int8_t*)(ws + 14*MB);   // [4][2048][128];  live during attn
  int8_t* vqp = (int8_t*)(ws + 15*MB);   // [4][2048][128];  live during attn
  float* xs  = (float*)(ws + 16*MB);
  float* wqs = xs + 2048;
  float* wks = wqs + 2048;
  float* wvs = wks + 512;
  float* qsc = wvs + 512;
  float* ksc = qsc + (size_t)NH*TT;
  float* vsc = ksc + (size_t)NKV*TT;
  // f32 ao [2048][2048]: 16 MB at ws+16.25MB.
  float* ao = (float*)(ws + 16*MB + 262144);
  // RoPE table: 1 MB over ao region (dead after proj; ao written by attn).
  float2* ropet = (float2*)(ws + 16*MB + 262144);
  // attn partial slots (64 KB each): slots 0..159 in ws[0..10MB); slots
  // 160..383 in d_out[0..14MB); m/l at d_out+15.5MB. All dead after merge.
  float* opA = (float*)(ws);
  float* opB = out;
  float* mlb = (float*)((char*)out + 15*MB + 524288);
  // digit-GEMM buffers (after merge, ws[0..16MB) and scale region dead):
  int8_t* ahi = (int8_t*)(ws);
  int8_t* alo = (int8_t*)(ws + 4*MB);
  int8_t* bhi = (int8_t*)(ws + 8*MB);
  int8_t* blo = (int8_t*)(ws + 12*MB);
  float* sa = (float*)(ws + 16*MB);
  float* sb = sa + 2048;

  quant_rows_kernel<<<5632, 256, 0, stream>>>(x, wq, wk, wv,
                                              qx, xs, qwq, wqs, qwk, wks, qwv, wvs,
                                              ropet);
  proj_kernel<<<768, 256, 0, stream>>>(
      qx, xs, qwq, wqs, qwk, wks, qwv, wvs, ropet,
      qqp, qsc, kqp, ksc, vqp, vsc);
  attn_mfma_kernel<<<480, 512, 0, stream>>>(
      qqp, qsc, kqp, ksc, vqp, vsc, ao, opA, opB, mlb);
  merge_kernel<<<160, 256, 0, stream>>>(opA, opB, mlb, ao);
  awquant_kernel<<<4096, 256, 0, stream>>>(ao, wo, ahi, alo, bhi, blo, sa, sb);
  wo_gemm_kernel<<<512, 256, 0, stream>>>(ahi, alo, bhi, blo, sa, sb, out);
}